// Round 3
// baseline (9420.985 us; speedup 1.0000x reference)
//
#include <hip/hip_runtime.h>
#include <math.h>

#define DMODEL 2048
#define NHEADS 16
#define DK     128
#define BATCH  4
#define SEQ    2048
#define MROWS  (BATCH*SEQ)   // 8192

// ---------------------------------------------------------------------------
// NT-GEMM tile core: C[m,n] = sum_k X[m,k] * W[n,k]
// X: [*,2048] row-major, W: [2048,2048] row-major. BM=BN=128, BK=16,
// 256 threads, 8x8 micro-tile. (unchanged: ~73% of fp32 vector peak)
// ---------------------------------------------------------------------------
__device__ __forceinline__ void gemm_tile_nt(const float* __restrict__ X,
                                             const float* __restrict__ W,
                                             int bm, int bn,
                                             float (&c)[8][8]) {
    __shared__ float As[16][132];   // [k][m], pad 132 (16B-aligned rows)
    __shared__ float Bs[16][132];   // [k][n]

    const int t    = threadIdx.x;
    const int r0   = t >> 2;          // 0..63 (tile row for staging)
    const int q4   = (t & 3) * 4;     // k-quad 0,4,8,12
    const int lane = t & 63;
    const int wave = t >> 6;
    const int row0 = (wave >> 1) * 64 + (lane >> 3) * 8;  // 0..120
    const int col0 = (wave & 1)  * 64 + (lane & 7)  * 8;  // 0..120

    const float* Xa = X + (size_t)(bm + r0)      * DMODEL + q4;
    const float* Xb = X + (size_t)(bm + r0 + 64) * DMODEL + q4;
    const float* Wa = W + (size_t)(bn + r0)      * DMODEL + q4;
    const float* Wb = W + (size_t)(bn + r0 + 64) * DMODEL + q4;

    for (int kt = 0; kt < DMODEL; kt += 16) {
        const float4 xa = *(const float4*)(Xa + kt);
        const float4 xb = *(const float4*)(Xb + kt);
        const float4 wa = *(const float4*)(Wa + kt);
        const float4 wb = *(const float4*)(Wb + kt);
        __syncthreads();   // previous compute done reading LDS
        As[q4+0][r0] = xa.x; As[q4+1][r0] = xa.y; As[q4+2][r0] = xa.z; As[q4+3][r0] = xa.w;
        As[q4+0][r0+64] = xb.x; As[q4+1][r0+64] = xb.y; As[q4+2][r0+64] = xb.z; As[q4+3][r0+64] = xb.w;
        Bs[q4+0][r0] = wa.x; Bs[q4+1][r0] = wa.y; Bs[q4+2][r0] = wa.z; Bs[q4+3][r0] = wa.w;
        Bs[q4+0][r0+64] = wb.x; Bs[q4+1][r0+64] = wb.y; Bs[q4+2][r0+64] = wb.z; Bs[q4+3][r0+64] = wb.w;
        __syncthreads();
#pragma unroll
        for (int kk = 0; kk < 16; ++kk) {
            const float4 a0 = *(const float4*)&As[kk][row0];
            const float4 a1 = *(const float4*)&As[kk][row0 + 4];
            const float4 b0 = *(const float4*)&Bs[kk][col0];
            const float4 b1 = *(const float4*)&Bs[kk][col0 + 4];
            const float a[8] = {a0.x,a0.y,a0.z,a0.w,a1.x,a1.y,a1.z,a1.w};
            const float b[8] = {b0.x,b0.y,b0.z,b0.w,b1.x,b1.y,b1.z,b1.w};
#pragma unroll
            for (int i = 0; i < 8; ++i)
#pragma unroll
                for (int j = 0; j < 8; ++j)
                    c[i][j] += a[i] * b[j];
        }
    }
}

__global__ __launch_bounds__(256)
void qkv_proj_kernel(const float* __restrict__ x,
                     const float* __restrict__ wq,
                     const float* __restrict__ wk,
                     const float* __restrict__ wv,
                     float* __restrict__ Qb, float* __restrict__ Kb,
                     float* __restrict__ Vb) {
    const int g  = blockIdx.x >> 4;
    const int nb = blockIdx.x & 15;         // head index
    const int bm = blockIdx.y * 128;
    const float* W = (g == 0) ? wq : (g == 1) ? wk : wv;
    float* outb    = (g == 0) ? Qb : (g == 1) ? Kb : Vb;

    float c[8][8] = {};
    gemm_tile_nt(x, W, bm, nb * 128, c);

    const int lane = threadIdx.x & 63;
    const int wave = threadIdx.x >> 6;
    const int row0 = (wave >> 1) * 64 + (lane >> 3) * 8;
    const int col0 = (wave & 1)  * 64 + (lane & 7)  * 8;   // = dk base
#pragma unroll
    for (int i = 0; i < 8; ++i) {
        const int m  = bm + row0 + i;
        const int bb = m >> 11;           // /SEQ
        const int ss = m & 2047;
        float* dst = outb + ((size_t)(bb * NHEADS + nb) * SEQ + ss) * DK + col0;
        *(float4*)(dst)     = make_float4(c[i][0], c[i][1], c[i][2], c[i][3]);
        *(float4*)(dst + 4) = make_float4(c[i][4], c[i][5], c[i][6], c[i][7]);
    }
}

__global__ __launch_bounds__(256)
void out_proj_kernel(const float* __restrict__ A,
                     const float* __restrict__ wo,
                     float* __restrict__ out) {
    const int bn = blockIdx.x * 128;
    const int bm = blockIdx.y * 128;
    float c[8][8] = {};
    gemm_tile_nt(A, wo, bm, bn, c);

    const int lane = threadIdx.x & 63;
    const int wave = threadIdx.x >> 6;
    const int row0 = (wave >> 1) * 64 + (lane >> 3) * 8;
    const int col0 = (wave & 1)  * 64 + (lane & 7)  * 8;
#pragma unroll
    for (int i = 0; i < 8; ++i) {
        float* dst = out + (size_t)(bm + row0 + i) * DMODEL + bn + col0;
        *(float4*)(dst)     = make_float4(c[i][0], c[i][1], c[i][2], c[i][3]);
        *(float4*)(dst + 4) = make_float4(c[i][4], c[i][5], c[i][6], c[i][7]);
    }
}

// ---------------------------------------------------------------------------
// Flash attention, fp32, 4-query register blocking, 8-key chunks.
// Grid: (S/128, B*H). 256 threads. Thread t: qslot = t>>3 (0..31), dg = t&7.
// Thread owns queries {q0 + qslot + 32j : j<4} and dims {dg*4 + 32c + e}.
// LDS tile = 16 keys, processed in two 8-key chunks so only s[4][8] (32
// floats) is live at once — R2's s[4][16] spilled to scratch (7.3 GB HBM
// fetch). kv/vv float4s are loaded per-key (transient).
// ---------------------------------------------------------------------------
__global__ __launch_bounds__(256)
void attn_kernel(const float* __restrict__ Q, const float* __restrict__ Kg,
                 const float* __restrict__ Vg, float* __restrict__ O) {
    __shared__ float Ks[16][128];
    __shared__ float Vs[16][128];

    const int bh = blockIdx.y;           // b*16 + h
    const int q0 = blockIdx.x * 128;
    const int t  = threadIdx.x;
    const int qs = t >> 3;               // 0..31
    const int dg = t & 7;                // 0..7
    const float scale = 0.08838834764831845f;  // 1/sqrt(128)

    float4 qr[4][4];
#pragma unroll
    for (int j = 0; j < 4; ++j) {
        const float* Qrow = Q + ((size_t)bh * SEQ + q0 + qs + 32 * j) * DK;
#pragma unroll
        for (int c = 0; c < 4; ++c)
            qr[j][c] = *(const float4*)(Qrow + dg * 4 + c * 32);
    }

    float4 o[4][4];
#pragma unroll
    for (int j = 0; j < 4; ++j)
#pragma unroll
        for (int c = 0; c < 4; ++c) o[j][c] = make_float4(0.f, 0.f, 0.f, 0.f);
    float m[4] = {-1e30f, -1e30f, -1e30f, -1e30f};
    float l[4] = {0.f, 0.f, 0.f, 0.f};

    const float* Kbase = Kg + (size_t)bh * SEQ * DK;
    const float* Vbase = Vg + (size_t)bh * SEQ * DK;

    for (int kt = 0; kt < SEQ; kt += 16) {
        __syncthreads();   // previous iteration done reading tiles
#pragma unroll
        for (int r = 0; r < 2; ++r) {
            const int f   = t + 256 * r;      // 0..511
            const int row = f >> 5;           // 0..15
            const int c4  = f & 31;
            *(float4*)&Ks[row][c4 * 4] = ((const float4*)(Kbase + (size_t)(kt + row) * DK))[c4];
            *(float4*)&Vs[row][c4 * 4] = ((const float4*)(Vbase + (size_t)(kt + row) * DK))[c4];
        }
        __syncthreads();

#pragma unroll
        for (int hc = 0; hc < 2; ++hc) {     // two 8-key chunks
            const int kb = hc * 8;
            float s[4][8];
#pragma unroll
            for (int k = 0; k < 8; ++k) {
                float4 kv[4];
#pragma unroll
                for (int c = 0; c < 4; ++c)
                    kv[c] = *(const float4*)&Ks[kb + k][dg * 4 + c * 32];
#pragma unroll
                for (int j = 0; j < 4; ++j) {
                    float acc = 0.f;
#pragma unroll
                    for (int c = 0; c < 4; ++c) {
                        acc += qr[j][c].x * kv[c].x + qr[j][c].y * kv[c].y
                             + qr[j][c].z * kv[c].z + qr[j][c].w * kv[c].w;
                    }
                    s[j][k] = acc;
                }
            }
            // butterfly-reduce partial dots over the 8 dg lanes (in-wave)
#pragma unroll
            for (int j = 0; j < 4; ++j)
#pragma unroll
                for (int k = 0; k < 8; ++k) {
                    float v = s[j][k];
                    v += __shfl_xor(v, 1);
                    v += __shfl_xor(v, 2);
                    v += __shfl_xor(v, 4);
                    s[j][k] = v * scale;
                }
            // online softmax (all 8 dg lanes compute identically)
#pragma unroll
            for (int j = 0; j < 4; ++j) {
                float mt = s[j][0];
#pragma unroll
                for (int k = 1; k < 8; ++k) mt = fmaxf(mt, s[j][k]);
                const float mnew = fmaxf(m[j], mt);
                const float corr = __expf(m[j] - mnew);
                float lsum = 0.f;
#pragma unroll
                for (int k = 0; k < 8; ++k) { s[j][k] = __expf(s[j][k] - mnew); lsum += s[j][k]; }
                l[j] = l[j] * corr + lsum;
#pragma unroll
                for (int c = 0; c < 4; ++c) {
                    o[j][c].x *= corr; o[j][c].y *= corr;
                    o[j][c].z *= corr; o[j][c].w *= corr;
                }
                m[j] = mnew;
            }
            // PV accumulate
#pragma unroll
            for (int k = 0; k < 8; ++k) {
                float4 vv[4];
#pragma unroll
                for (int c = 0; c < 4; ++c)
                    vv[c] = *(const float4*)&Vs[kb + k][dg * 4 + c * 32];
#pragma unroll
                for (int j = 0; j < 4; ++j) {
                    const float p = s[j][k];
#pragma unroll
                    for (int c = 0; c < 4; ++c) {
                        o[j][c].x += p * vv[c].x; o[j][c].y += p * vv[c].y;
                        o[j][c].z += p * vv[c].z; o[j][c].w += p * vv[c].w;
                    }
                }
            }
        }
    }

    const int bb = bh >> 4;
    const int h  = bh & 15;
#pragma unroll
    for (int j = 0; j < 4; ++j) {
        const float inv = 1.f / l[j];
        const size_t orow = ((size_t)bb * SEQ + q0 + qs + 32 * j) * DMODEL + (size_t)h * DK;
#pragma unroll
        for (int c = 0; c < 4; ++c) {
            const float4 ov = make_float4(o[j][c].x * inv, o[j][c].y * inv,
                                          o[j][c].z * inv, o[j][c].w * inv);
            *(float4*)(O + orow + dg * 4 + c * 32) = ov;
        }
    }
}

extern "C" void kernel_launch(void* const* d_in, const int* in_sizes, int n_in,
                              void* d_out, int out_size, void* d_ws, size_t ws_size,
                              hipStream_t stream) {
    const float* x  = (const float*)d_in[0];
    const float* wq = (const float*)d_in[1];
    const float* wk = (const float*)d_in[2];
    const float* wv = (const float*)d_in[3];
    const float* wo = (const float*)d_in[4];
    float* out = (float*)d_out;
    float* ws  = (float*)d_ws;

    // workspace layout (floats): Q,K,V in [B,H,S,DK]; attnO in [B,S,H*DK]
    float* Qb = ws;
    float* Kb = ws + (size_t)16777216;
    float* Vb = ws + (size_t)33554432;
    float* Ob = ws + (size_t)50331648;

    dim3 blk(256);
    qkv_proj_kernel<<<dim3(48, 64), blk, 0, stream>>>(x, wq, wk, wv, Qb, Kb, Vb);
    attn_kernel<<<dim3(SEQ / 128, BATCH * NHEADS), blk, 0, stream>>>(Qb, Kb, Vb, Ob);
    out_proj_kernel<<<dim3(16, 64), blk, 0, stream>>>(Ob, wo, out);
}

// Round 4
// 3791.933 us; speedup vs baseline: 2.4845x; 2.4845x over previous
//
#include <hip/hip_runtime.h>
#include <math.h>

#define DMODEL 2048
#define NHEADS 16
#define DK     128
#define BATCH  4
#define SEQ    2048
#define MROWS  (BATCH*SEQ)   // 8192

typedef unsigned short u16;
typedef short s16x8 __attribute__((ext_vector_type(8)));
typedef u16   u16x8 __attribute__((ext_vector_type(8)));
typedef float f32x4 __attribute__((ext_vector_type(4)));
typedef unsigned int u32x4 __attribute__((ext_vector_type(4)));

#define MFMA16(a, b, c) __builtin_amdgcn_mfma_f32_16x16x32_bf16((a), (b), (c), 0, 0, 0)

__device__ __forceinline__ u16 f2bf(float f) {       // RNE fp32 -> bf16 bits
    unsigned u = __builtin_bit_cast(unsigned, f);
    unsigned r = (u + 0x7fffu + ((u >> 16) & 1u)) >> 16;
    return (u16)r;
}
__device__ __forceinline__ float bf2f(u16 h) {
    unsigned u = ((unsigned)h) << 16;
    return __builtin_bit_cast(float, u);
}

// ---------------------------------------------------------------------------
// NT-GEMM tile core: C[m,n] = sum_k X[m,k] * W[n,k]  (fp32 vector, ~73% peak)
// ---------------------------------------------------------------------------
__device__ __forceinline__ void gemm_tile_nt(const float* __restrict__ X,
                                             const float* __restrict__ W,
                                             int bm, int bn,
                                             float (&c)[8][8]) {
    __shared__ float As[16][132];
    __shared__ float Bs[16][132];

    const int t    = threadIdx.x;
    const int r0   = t >> 2;
    const int q4   = (t & 3) * 4;
    const int lane = t & 63;
    const int wave = t >> 6;
    const int row0 = (wave >> 1) * 64 + (lane >> 3) * 8;
    const int col0 = (wave & 1)  * 64 + (lane & 7)  * 8;

    const float* Xa = X + (size_t)(bm + r0)      * DMODEL + q4;
    const float* Xb = X + (size_t)(bm + r0 + 64) * DMODEL + q4;
    const float* Wa = W + (size_t)(bn + r0)      * DMODEL + q4;
    const float* Wb = W + (size_t)(bn + r0 + 64) * DMODEL + q4;

    for (int kt = 0; kt < DMODEL; kt += 16) {
        const float4 xa = *(const float4*)(Xa + kt);
        const float4 xb = *(const float4*)(Xb + kt);
        const float4 wa = *(const float4*)(Wa + kt);
        const float4 wb = *(const float4*)(Wb + kt);
        __syncthreads();
        As[q4+0][r0] = xa.x; As[q4+1][r0] = xa.y; As[q4+2][r0] = xa.z; As[q4+3][r0] = xa.w;
        As[q4+0][r0+64] = xb.x; As[q4+1][r0+64] = xb.y; As[q4+2][r0+64] = xb.z; As[q4+3][r0+64] = xb.w;
        Bs[q4+0][r0] = wa.x; Bs[q4+1][r0] = wa.y; Bs[q4+2][r0] = wa.z; Bs[q4+3][r0] = wa.w;
        Bs[q4+0][r0+64] = wb.x; Bs[q4+1][r0+64] = wb.y; Bs[q4+2][r0+64] = wb.z; Bs[q4+3][r0+64] = wb.w;
        __syncthreads();
#pragma unroll
        for (int kk = 0; kk < 16; ++kk) {
            const float4 a0 = *(const float4*)&As[kk][row0];
            const float4 a1 = *(const float4*)&As[kk][row0 + 4];
            const float4 b0 = *(const float4*)&Bs[kk][col0];
            const float4 b1 = *(const float4*)&Bs[kk][col0 + 4];
            const float a[8] = {a0.x,a0.y,a0.z,a0.w,a1.x,a1.y,a1.z,a1.w};
            const float b[8] = {b0.x,b0.y,b0.z,b0.w,b1.x,b1.y,b1.z,b1.w};
#pragma unroll
            for (int i = 0; i < 8; ++i)
#pragma unroll
                for (int j = 0; j < 8; ++j)
                    c[i][j] += a[i] * b[j];
        }
    }
}

// QKV projection. Q,K -> bf16 hi/lo [BH,S,128] (Q pre-scaled by 1/sqrt(dk)).
// V -> bf16 (single) TRANSPOSED [BH,128,S].
__global__ __launch_bounds__(256)
void qkv_proj_kernel(const float* __restrict__ x,
                     const float* __restrict__ wq,
                     const float* __restrict__ wk,
                     const float* __restrict__ wv,
                     u16* __restrict__ Qhi, u16* __restrict__ Qlo,
                     u16* __restrict__ Khi, u16* __restrict__ Klo,
                     u16* __restrict__ Vt) {
    const int g  = blockIdx.x >> 4;
    const int nb = blockIdx.x & 15;         // head index
    const int bm = blockIdx.y * 128;
    const float* W = (g == 0) ? wq : (g == 1) ? wk : wv;

    float c[8][8] = {};
    gemm_tile_nt(x, W, bm, nb * 128, c);

    const int lane = threadIdx.x & 63;
    const int wave = threadIdx.x >> 6;
    const int row0 = (wave >> 1) * 64 + (lane >> 3) * 8;
    const int col0 = (wave & 1)  * 64 + (lane & 7)  * 8;   // dk base

    const int m0 = bm + row0;
    const int bb = m0 >> 11;            // batch (all 8 rows same 128-block)
    const int ss0 = m0 & 2047;
    const int bh = bb * NHEADS + nb;

    if (g < 2) {
        u16* hi_g = (g == 0) ? Qhi : Khi;
        u16* lo_g = (g == 0) ? Qlo : Klo;
        const float sc = (g == 0) ? 0.08838834764831845f : 1.0f;
#pragma unroll
        for (int i = 0; i < 8; ++i) {
            u16x8 h8, l8;
#pragma unroll
            for (int j = 0; j < 8; ++j) {
                const float y = c[i][j] * sc;
                const u16 hb = f2bf(y);
                h8[j] = hb;
                l8[j] = f2bf(y - bf2f(hb));
            }
            const size_t base = ((size_t)bh * SEQ + ss0 + i) * DK + col0;
            *(u16x8*)(hi_g + base) = h8;
            *(u16x8*)(lo_g + base) = l8;
        }
    } else {
        // V transposed: Vt[bh][d][s]
#pragma unroll
        for (int j = 0; j < 8; ++j) {
            u16x8 v8;
#pragma unroll
            for (int i = 0; i < 8; ++i) v8[i] = f2bf(c[i][j]);
            const size_t base = ((size_t)bh * DK + col0 + j) * SEQ + ss0;
            *(u16x8*)(Vt + base) = v8;
        }
    }
}

__global__ __launch_bounds__(256)
void out_proj_kernel(const float* __restrict__ A,
                     const float* __restrict__ wo,
                     float* __restrict__ out) {
    const int bn = blockIdx.x * 128;
    const int bm = blockIdx.y * 128;
    float c[8][8] = {};
    gemm_tile_nt(A, wo, bm, bn, c);

    const int lane = threadIdx.x & 63;
    const int wave = threadIdx.x >> 6;
    const int row0 = (wave >> 1) * 64 + (lane >> 3) * 8;
    const int col0 = (wave & 1)  * 64 + (lane & 7)  * 8;
#pragma unroll
    for (int i = 0; i < 8; ++i) {
        float* dst = out + (size_t)(bm + row0 + i) * DMODEL + bn + col0;
        *(float4*)(dst)     = make_float4(c[i][0], c[i][1], c[i][2], c[i][3]);
        *(float4*)(dst + 4) = make_float4(c[i][4], c[i][5], c[i][6], c[i][7]);
    }
}

// ---------------------------------------------------------------------------
// MFMA flash attention, split-bf16.
// Grid (SEQ/64, B*H), 256 threads = 4 waves; wave owns 16 queries.
// Per 32-key tile: S = Qhi*Khi + Qlo*Khi + Qhi*Klo (16x16x32 MFMA, 2 n-tiles
// x 4 k-blocks x 3 = 24 MFMA), online softmax on C-layout regs, P (hi/lo
// packed per word) round-trips LDS to A-layout, PV: O += (Phi+Plo)*V
// (8 d-tiles x 2 = 16 MFMA). V is staged from the pre-transposed global Vt.
// LDS strides 136/40/36 chosen for 16B row alignment + even bank coverage.
// ---------------------------------------------------------------------------
__global__ __launch_bounds__(256)
void attn_kernel(const u16* __restrict__ Qhi, const u16* __restrict__ Qlo,
                 const u16* __restrict__ KhiG, const u16* __restrict__ KloG,
                 const u16* __restrict__ VtG, float* __restrict__ O) {
    __shared__ u16 Khs[32][136];
    __shared__ u16 Kls[32][136];
    __shared__ u16 Vs[128][40];          // [dim][key]
    __shared__ unsigned int Pb[64][36];  // packed (phi | plo<<16)

    const int bh = blockIdx.y;
    const int q0 = blockIdx.x * 64;
    const int t  = threadIdx.x;
    const int l  = t & 63;
    const int w  = t >> 6;
    const int lm = l & 15;       // "m/n" lane index
    const int lg = l >> 4;       // k-quad
    const int woff = w * 16;

    // ---- load Q fragments (A-layout: m=lm, k=kb*32+lg*8+j) ----
    s16x8 qh[4], ql[4];
    {
        const size_t qrow = (size_t)bh * SEQ + q0 + woff + lm;
#pragma unroll
        for (int kb = 0; kb < 4; ++kb) {
            const size_t off = qrow * DK + kb * 32 + lg * 8;
            qh[kb] = *(const s16x8*)(Qhi + off);
            ql[kb] = *(const s16x8*)(Qlo + off);
        }
    }

    f32x4 o[8];
#pragma unroll
    for (int nt = 0; nt < 8; ++nt) o[nt] = (f32x4){0.f, 0.f, 0.f, 0.f};
    float m[4] = {-1e30f, -1e30f, -1e30f, -1e30f};
    float lsm[4] = {0.f, 0.f, 0.f, 0.f};

    // staging indices
    const int skey = t >> 3;            // 0..31
    const int sdb  = (t & 7) * 16;      // dim base for K staging
    const int vdim = t >> 1;            // 0..127
    const int vkb  = (t & 1) * 16;      // key base for V staging
    const u16* Kh_base = KhiG + ((size_t)bh * SEQ + skey) * DK + sdb;
    const u16* Kl_base = KloG + ((size_t)bh * SEQ + skey) * DK + sdb;
    const u16* Vt_base = VtG + ((size_t)bh * DK + vdim) * SEQ + vkb;

    for (int kt = 0; kt < SEQ; kt += 32) {
        __syncthreads();
        {
            const u16* kh = Kh_base + (size_t)kt * DK;
            const u16* klp = Kl_base + (size_t)kt * DK;
            u16x8 a0 = *(const u16x8*)kh;
            u16x8 a1 = *(const u16x8*)(kh + 8);
            u16x8 b0 = *(const u16x8*)klp;
            u16x8 b1 = *(const u16x8*)(klp + 8);
            *(u16x8*)&Khs[skey][sdb]     = a0;
            *(u16x8*)&Khs[skey][sdb + 8] = a1;
            *(u16x8*)&Kls[skey][sdb]     = b0;
            *(u16x8*)&Kls[skey][sdb + 8] = b1;
            const u16* vp = Vt_base + kt;
            u16x8 v0 = *(const u16x8*)vp;
            u16x8 v1 = *(const u16x8*)(vp + 8);
            *(u16x8*)&Vs[vdim][vkb]     = v0;
            *(u16x8*)&Vs[vdim][vkb + 8] = v1;
        }
        __syncthreads();

        // ---- S phase ----
        f32x4 sacc[2];
#pragma unroll
        for (int nt = 0; nt < 2; ++nt) {
            f32x4 acc = (f32x4){0.f, 0.f, 0.f, 0.f};
#pragma unroll
            for (int kb = 0; kb < 4; ++kb) {
                const s16x8 bh_f = *(const s16x8*)&Khs[nt * 16 + lm][kb * 32 + lg * 8];
                const s16x8 bl_f = *(const s16x8*)&Kls[nt * 16 + lm][kb * 32 + lg * 8];
                acc = MFMA16(qh[kb], bh_f, acc);
                acc = MFMA16(ql[kb], bh_f, acc);
                acc = MFMA16(qh[kb], bl_f, acc);
            }
            sacc[nt] = acc;
        }

        // ---- online softmax (rows = (lg*4+r), cols = nt*16+lm) ----
        float corr[4], p0[4], p1[4];
#pragma unroll
        for (int r = 0; r < 4; ++r) {
            float v = fmaxf(sacc[0][r], sacc[1][r]);
            v = fmaxf(v, __shfl_xor(v, 1));
            v = fmaxf(v, __shfl_xor(v, 2));
            v = fmaxf(v, __shfl_xor(v, 4));
            v = fmaxf(v, __shfl_xor(v, 8));
            const float mnew = fmaxf(m[r], v);
            corr[r] = __expf(m[r] - mnew);
            m[r] = mnew;
            p0[r] = __expf(sacc[0][r] - mnew);
            p1[r] = __expf(sacc[1][r] - mnew);
            float ls = p0[r] + p1[r];
            ls += __shfl_xor(ls, 1);
            ls += __shfl_xor(ls, 2);
            ls += __shfl_xor(ls, 4);
            ls += __shfl_xor(ls, 8);
            lsm[r] = lsm[r] * corr[r] + ls;
        }
#pragma unroll
        for (int nt = 0; nt < 8; ++nt) {
#pragma unroll
            for (int r = 0; r < 4; ++r) o[nt][r] *= corr[r];
        }

        // ---- write P to LDS (packed hi|lo), C-layout -> A-layout ----
#pragma unroll
        for (int r = 0; r < 4; ++r) {
            const int row = woff + lg * 4 + r;
            const u16 h0 = f2bf(p0[r]);
            const u16 l0 = f2bf(p0[r] - bf2f(h0));
            Pb[row][lm] = (unsigned)h0 | ((unsigned)l0 << 16);
            const u16 h1 = f2bf(p1[r]);
            const u16 l1 = f2bf(p1[r] - bf2f(h1));
            Pb[row][16 + lm] = (unsigned)h1 | ((unsigned)l1 << 16);
        }

        // ---- read P fragments (A-layout: m=lm, k=lg*8+j), unpack hi/lo ----
        const u32x4 r0 = *(const u32x4*)&Pb[woff + lm][lg * 8];
        const u32x4 r1 = *(const u32x4*)&Pb[woff + lm][lg * 8 + 4];
        u32x4 phw, plw;
        phw[0] = (r0[0] & 0xffffu) | (r0[1] << 16);
        phw[1] = (r0[2] & 0xffffu) | (r0[3] << 16);
        phw[2] = (r1[0] & 0xffffu) | (r1[1] << 16);
        phw[3] = (r1[2] & 0xffffu) | (r1[3] << 16);
        plw[0] = (r0[0] >> 16) | (r0[1] & 0xffff0000u);
        plw[1] = (r0[2] >> 16) | (r0[3] & 0xffff0000u);
        plw[2] = (r1[0] >> 16) | (r1[1] & 0xffff0000u);
        plw[3] = (r1[2] >> 16) | (r1[3] & 0xffff0000u);
        const s16x8 pHf = __builtin_bit_cast(s16x8, phw);
        const s16x8 pLf = __builtin_bit_cast(s16x8, plw);

        // ---- PV phase: O[q][d] += P * V ----
#pragma unroll
        for (int nt = 0; nt < 8; ++nt) {
            const s16x8 vf = *(const s16x8*)&Vs[nt * 16 + lm][lg * 8];
            o[nt] = MFMA16(pHf, vf, o[nt]);
            o[nt] = MFMA16(pLf, vf, o[nt]);
        }
    }

    // ---- epilogue: divide by l, write Ob[b][s][h*128+d] fp32 ----
    const int bb = bh >> 4;
    const int h  = bh & 15;
    float inv[4];
#pragma unroll
    for (int r = 0; r < 4; ++r) inv[r] = 1.f / lsm[r];
#pragma unroll
    for (int nt = 0; nt < 8; ++nt) {
#pragma unroll
        for (int r = 0; r < 4; ++r) {
            const int qrow = q0 + woff + lg * 4 + r;
            O[((size_t)bb * SEQ + qrow) * DMODEL + h * DK + nt * 16 + lm] = o[nt][r] * inv[r];
        }
    }
}

extern "C" void kernel_launch(void* const* d_in, const int* in_sizes, int n_in,
                              void* d_out, int out_size, void* d_ws, size_t ws_size,
                              hipStream_t stream) {
    const float* x  = (const float*)d_in[0];
    const float* wq = (const float*)d_in[1];
    const float* wk = (const float*)d_in[2];
    const float* wv = (const float*)d_in[3];
    const float* wo = (const float*)d_in[4];
    float* out = (float*)d_out;

    // ws layout: 5 bf16 arrays of 16.78M elems (33.55MB each) + Ob fp32 67MB
    const size_t NE = (size_t)BATCH * NHEADS * SEQ * DK;   // 16,777,216
    u16* Qhi = (u16*)d_ws;
    u16* Qlo = Qhi + NE;
    u16* Khi = Qlo + NE;
    u16* Klo = Khi + NE;
    u16* Vt  = Klo + NE;
    float* Ob = (float*)(Vt + NE);

    dim3 blk(256);
    qkv_proj_kernel<<<dim3(48, 64), blk, 0, stream>>>(x, wq, wk, wv,
                                                      Qhi, Qlo, Khi, Klo, Vt);
    attn_kernel<<<dim3(SEQ / 64, BATCH * NHEADS), blk, 0, stream>>>(Qhi, Qlo, Khi, Klo, Vt, Ob);
    out_proj_kernel<<<dim3(16, 64), blk, 0, stream>>>(Ob, wo, out);
}